// Round 5
// baseline (643.341 us; speedup 1.0000x reference)
//
#include <hip/hip_runtime.h>
#include <hip/hip_bf16.h>
#include <cstdint>
#include <cstddef>

#define N_NODES 20000
#define F_IN    2000
#define H_DIM   128
#define L_DIM   15
#define K_PAD   2048      // padded K for xb/w1r layouts
#define N1      512       // 4 hops * 128
#define BM      128
#define BN      128
#define BK      32
#define I_TILES 157       // ceil(20000/128)

typedef __attribute__((ext_vector_type(4))) float f32x4;
typedef __attribute__((ext_vector_type(8))) short s16x8;
typedef __attribute__((ext_vector_type(8))) unsigned short u16x8;

__device__ __forceinline__ unsigned short f2bf(float f) {
  unsigned int u = __float_as_uint(f);
  u += 0x7fff + ((u >> 16) & 1);   // RNE
  return (unsigned short)(u >> 16);
}

__device__ __forceinline__ unsigned int pkbf(float a, float b) {
  union { __hip_bfloat162 h; unsigned int u; } cv;
  cv.h = __float22bfloat162_rn(make_float2(a, b));
  return cv.u;
}

__device__ __forceinline__ float2 bf2f(unsigned int u) {
  float2 r;
  r.x = __uint_as_float(u << 16);
  r.y = __uint_as_float(u & 0xffff0000u);
  return r;
}

// ---- x (fp32 [20000][2000]) -> bf16 [20000][2048], zero pad cols; 8 elems/thread ----
__global__ __launch_bounds__(256) void k_cvt_x(const float* __restrict__ x,
                                               unsigned short* __restrict__ xb) {
  unsigned int t = blockIdx.x * 256u + threadIdx.x;
  unsigned int row = t >> 8;
  unsigned int colB = (t & 255u) * 8u;
  u16x8 o = {0, 0, 0, 0, 0, 0, 0, 0};
  if (colB < F_IN) {                       // F_IN % 8 == 0: all-or-none valid
    const float4 a = *(const float4*)(x + (size_t)row * F_IN + colB);
    const float4 b = *(const float4*)(x + (size_t)row * F_IN + colB + 4);
    o[0] = f2bf(a.x); o[1] = f2bf(a.y); o[2] = f2bf(a.z); o[3] = f2bf(a.w);
    o[4] = f2bf(b.x); o[5] = f2bf(b.y); o[6] = f2bf(b.z); o[7] = f2bf(b.w);
  }
  *(u16x8*)(xb + (size_t)t * 8) = o;
}

// ---- W1 [8000][128] -> bf16 B^T [512][2048] via coalesced read + LDS transpose ----
__global__ __launch_bounds__(256) void k_cvt_w1(const float* __restrict__ W1,
                                                unsigned short* __restrict__ bt) {
  __shared__ unsigned short tile[128 * 67];
  const int hop = blockIdx.x >> 5;
  const int k0  = (blockIdx.x & 31) * 64;
  const int t = threadIdx.x;
#pragma unroll
  for (int it = 0; it < 8; ++it) {
    int f4 = it * 256 + t;
    int r  = f4 >> 5;
    int c4 = f4 & 31;
    int k = k0 + r;
    float4 v = make_float4(0.f, 0.f, 0.f, 0.f);
    if (k < F_IN) v = *(const float4*)(W1 + (size_t)(hop * F_IN + k) * H_DIM + c4 * 4);
    tile[(c4 * 4 + 0) * 67 + r] = f2bf(v.x);
    tile[(c4 * 4 + 1) * 67 + r] = f2bf(v.y);
    tile[(c4 * 4 + 2) * 67 + r] = f2bf(v.z);
    tile[(c4 * 4 + 3) * 67 + r] = f2bf(v.w);
  }
  __syncthreads();
  const int c = t >> 1, kh = (t & 1) * 32;
  unsigned short* dst = bt + (size_t)(hop * 128 + c) * K_PAD + k0 + kh;
  const unsigned short* srcp = tile + c * 67 + kh;
#pragma unroll
  for (int q = 0; q < 4; ++q) {
    u16x8 o;
#pragma unroll
    for (int e = 0; e < 8; ++e) o[e] = srcp[q * 8 + e];
    *(u16x8*)(dst + q * 8) = o;
  }
}

// ---- K-split-2 bf16 MFMA GEMM, pure async staging, atomic fp32 accumulate ----
// grid = 1280: xcd=b&7; mid=(b>>3)&7 -> j_tile=mid&3, ks=mid>>2; i_tile=(b&7)+8*(b>>6).
// All 8 (j,ks) blocks of an i_tile share b mod 8 -> same XCD -> A rows L2-shared.
__global__ __launch_bounds__(256) void k_gemm1(const unsigned short* __restrict__ A,
                                               const unsigned short* __restrict__ B,
                                               float* __restrict__ C0) {
  __shared__ unsigned short As[BM * BK];
  __shared__ unsigned short Bs[BN * BK];
  const int b = blockIdx.x;
  const int i_tile = (b & 7) + 8 * (b >> 6);
  const int mid = (b >> 3) & 7;
  const int j_tile = mid & 3;
  const int ks = mid >> 2;
  if (i_tile >= I_TILES) return;
  const int rowA0 = i_tile * BM;
  const int colB0 = j_tile * BN;
  const int tid  = threadIdx.x;
  const int lane = tid & 63;
  const int wave = tid >> 6;
  const int wm = (wave >> 1) * 64;
  const int wn = (wave & 1) * 64;
  const int quad = lane >> 4;
  const int l15  = lane & 15;
  f32x4 acc[4][4] = {};

  const int kend = ks ? F_IN : 1024;   // both xb and w1r zero-padded to 2048
  for (int kt = ks * 1024; kt < kend; kt += BK) {
#pragma unroll
    for (int r = 0; r < 2; ++r) {
      int c = r * 256 + tid;
      int row = c >> 2;
      int kc = (c & 3) * 8;
      const unsigned short* ga = A + (size_t)(rowA0 + row) * K_PAD + kt + kc;
      __builtin_amdgcn_global_load_lds((const __attribute__((address_space(1))) void*)ga,
                                       (__attribute__((address_space(3))) void*)(As + c * 8),
                                       16, 0, 0);
      const unsigned short* gb = B + (size_t)(colB0 + row) * K_PAD + kt + kc;
      __builtin_amdgcn_global_load_lds((const __attribute__((address_space(1))) void*)gb,
                                       (__attribute__((address_space(3))) void*)(Bs + c * 8),
                                       16, 0, 0);
    }
    __syncthreads();
    s16x8 af[4], bfr[4];
#pragma unroll
    for (int i = 0; i < 4; ++i)
      af[i] = *(const s16x8*)(As + (wm + i * 16 + l15) * BK + quad * 8);
#pragma unroll
    for (int j = 0; j < 4; ++j)
      bfr[j] = *(const s16x8*)(Bs + (wn + j * 16 + l15) * BK + quad * 8);
#pragma unroll
    for (int i = 0; i < 4; ++i)
#pragma unroll
      for (int j = 0; j < 4; ++j)
        acc[i][j] = __builtin_amdgcn_mfma_f32_16x16x32_bf16(af[i], bfr[j], acc[i][j], 0, 0, 0);
    __syncthreads();
  }

  // note: for i_tile==156, staged A rows >=20000 read garbage past xb (still in
  // d_ws, bf16-finite); their acc elements are discarded by the row guard below.
#pragma unroll
  for (int i = 0; i < 4; ++i) {
    int row0 = rowA0 + wm + i * 16 + quad * 4;
#pragma unroll
    for (int j = 0; j < 4; ++j) {
      int col = colB0 + wn + j * 16 + l15;
#pragma unroll
      for (int r = 0; r < 4; ++r) {
        int row = row0 + r;
        if (row < N_NODES)
          unsafeAtomicAdd(&C0[(size_t)row * N1 + col], acc[i][j][r]);  // native f32 fadd
      }
    }
  }
}

// ---- Yb3 bf16 <- C0 cols [384,512) ----
__global__ __launch_bounds__(256) void k_mkYb3(const float* __restrict__ C0,
                                               unsigned short* __restrict__ Yb3) {
  unsigned int t = blockIdx.x * 256u + threadIdx.x;   // 20000*32 threads
  unsigned int row = t >> 5;
  unsigned int c4 = (t & 31u) * 4u;
  float4 s = *(const float4*)(C0 + (size_t)row * N1 + 384 + c4);
  *(uint2*)(Yb3 + (size_t)row * H_DIM + c4) = make_uint2(pkbf(s.x, s.y), pkbf(s.z, s.w));
}

// ---- CSR build ----
__global__ __launch_bounds__(256) void k_hist(const int* __restrict__ dst,
                                              int* __restrict__ deg, int E) {
  int i = blockIdx.x * 256 + threadIdx.x;
  int e = i * 4;
  if (e + 4 <= E) {
    int4 d4 = *(const int4*)(dst + e);
    atomicAdd(&deg[d4.x], 1); atomicAdd(&deg[d4.y], 1);
    atomicAdd(&deg[d4.z], 1); atomicAdd(&deg[d4.w], 1);
  } else {
    for (; e < E; ++e) atomicAdd(&deg[dst[e]], 1);
  }
}

__global__ __launch_bounds__(1024) void k_scan(const int* __restrict__ deg,
                                               int* __restrict__ rowStart,
                                               int* __restrict__ cursor) {
  __shared__ int sums[1024];
  const int t = threadIdx.x;
  const int chunk = (N_NODES + 1023) / 1024;
  int lo = t * chunk;
  int hi = lo + chunk; if (hi > N_NODES) hi = N_NODES;
  int s = 0;
  for (int i = lo; i < hi; ++i) s += deg[i];
  sums[t] = s;
  __syncthreads();
  for (int off = 1; off < 1024; off <<= 1) {
    int v = sums[t];
    int u = (t >= off) ? sums[t - off] : 0;
    __syncthreads();
    sums[t] = v + u;
    __syncthreads();
  }
  int run = sums[t] - s;
  for (int i = lo; i < hi; ++i) {
    rowStart[i] = run; cursor[i] = run; run += deg[i];
  }
  if (t == 1023) rowStart[N_NODES] = run;
}

__global__ __launch_bounds__(256) void k_scatter(const int* __restrict__ src,
                                                 const int* __restrict__ dst,
                                                 const float* __restrict__ w,
                                                 int* cursor,
                                                 int2* __restrict__ eSW, int E) {
  int e = blockIdx.x * 256 + threadIdx.x;
  if (e >= E) return;
  int p = atomicAdd(&cursor[dst[e]], 1);
  eSW[p] = make_int2(src[e], __float_as_int(w[e]));
}

// ---- pull-propagation, 128-wide, 2 waves per row (edge-striped) ----
// mode 0: outb = bf16(addv + acc)   mode 1: outf = relu(BN(addv + acc + b1))
__global__ __launch_bounds__(256) void k_prop128c(const int* __restrict__ rowStart,
    const int2* __restrict__ eSW,
    const unsigned short* __restrict__ gsrc,   // bf16 [N_NODES][128]
    const float* __restrict__ addv, int addStride, int addOff,
    unsigned short* __restrict__ outb, float* __restrict__ outf,
    const float* __restrict__ b1, const float* __restrict__ gamma,
    const float* __restrict__ beta, const float* __restrict__ mean,
    const float* __restrict__ var, int doBN) {
  __shared__ float red[2][128];
  const int lane = threadIdx.x & 63;
  const int wave = threadIdx.x >> 6;
  const int rb = wave >> 1;                 // row-in-block 0/1
  const int h  = wave & 1;                  // edge stripe
  const int d = blockIdx.x * 2 + rb;
  const int s0 = rowStart[d], s1 = rowStart[d + 1];
  const int c2 = lane * 2;
  float ax = 0.f, ay = 0.f;
  int j = s0 + h;
  for (; j + 6 < s1; j += 8) {              // 4 edges per iter (stride 2)
    int2 e0 = eSW[j], e1 = eSW[j + 2], e2 = eSW[j + 4], e3 = eSW[j + 6];
    unsigned int g0 = *(const unsigned int*)(gsrc + (size_t)e0.x * H_DIM + c2);
    unsigned int g1 = *(const unsigned int*)(gsrc + (size_t)e1.x * H_DIM + c2);
    unsigned int g2 = *(const unsigned int*)(gsrc + (size_t)e2.x * H_DIM + c2);
    unsigned int g3 = *(const unsigned int*)(gsrc + (size_t)e3.x * H_DIM + c2);
    float2 v0 = bf2f(g0), v1 = bf2f(g1), v2 = bf2f(g2), v3 = bf2f(g3);
    float w0 = __int_as_float(e0.y), w1 = __int_as_float(e1.y);
    float w2 = __int_as_float(e2.y), w3 = __int_as_float(e3.y);
    ax = fmaf(w0, v0.x, ax); ay = fmaf(w0, v0.y, ay);
    ax = fmaf(w1, v1.x, ax); ay = fmaf(w1, v1.y, ay);
    ax = fmaf(w2, v2.x, ax); ay = fmaf(w2, v2.y, ay);
    ax = fmaf(w3, v3.x, ax); ay = fmaf(w3, v3.y, ay);
  }
  for (; j < s1; j += 2) {
    int2 e = eSW[j];
    float2 v = bf2f(*(const unsigned int*)(gsrc + (size_t)e.x * H_DIM + c2));
    float w = __int_as_float(e.y);
    ax = fmaf(w, v.x, ax); ay = fmaf(w, v.y, ay);
  }
  if (h) { red[rb][c2] = ax; red[rb][c2 + 1] = ay; }
  __syncthreads();
  if (h) return;
  ax += red[rb][c2]; ay += red[rb][c2 + 1];
  float2 av = *(const float2*)(addv + (size_t)d * addStride + addOff + c2);
  float r0 = av.x + ax, r1 = av.y + ay;
  if (doBN) {
    float2 bb = *(const float2*)(b1 + c2);
    float2 gg = *(const float2*)(gamma + c2);
    float2 be = *(const float2*)(beta + c2);
    float2 mm = *(const float2*)(mean + c2);
    float2 vv = *(const float2*)(var + c2);
    r0 = (r0 + bb.x - mm.x) * rsqrtf(vv.x + 1e-3f) * gg.x + be.x;
    r1 = (r1 + bb.y - mm.y) * rsqrtf(vv.y + 1e-3f) * gg.y + be.y;
    r0 = r0 > 0.f ? r0 : 0.f;
    r1 = r1 > 0.f ? r1 : 0.f;
    *(float2*)(outf + (size_t)d * H_DIM + c2) = make_float2(r0, r1);
  } else {
    *(unsigned int*)(outb + (size_t)d * H_DIM + c2) = pkbf(r0, r1);
  }
}

// ---- Y2[20000][60] = H @ W2 (4 hop-blocks of [128][15]); fp32 ----
__global__ __launch_bounds__(256) void k_gemm2(const float* __restrict__ Hh,
                                               const float* __restrict__ W2,
                                               float* __restrict__ Y2) {
  __shared__ float w2s[512 * 15];
  for (int i = threadIdx.x; i < 512 * 15; i += 256) w2s[i] = W2[i];
  __syncthreads();
  const int c = threadIdx.x & 63;
  const int d = blockIdx.x * 4 + (threadIdx.x >> 6);
  if (c >= 60 || d >= N_NODES) return;
  const int hop = c / 15, j = c % 15;
  const float4* hr4 = (const float4*)(Hh + (size_t)d * H_DIM);
  float acc = 0.f;
#pragma unroll 8
  for (int k4 = 0; k4 < 32; ++k4) {
    float4 h = hr4[k4];
    const float* wp = w2s + ((hop << 7) + k4 * 4) * 15 + j;
    acc = fmaf(h.x, wp[0],  acc);
    acc = fmaf(h.y, wp[15], acc);
    acc = fmaf(h.z, wp[30], acc);
    acc = fmaf(h.w, wp[45], acc);
  }
  Y2[(size_t)d * 60 + c] = acc;
}

// ---- pull-propagation, 15-wide fp32 ----
__global__ __launch_bounds__(256) void k_prop15(const int* __restrict__ rowStart,
    const int2* __restrict__ eSW,
    const float* __restrict__ in, int inStride, int inOff,
    const float* __restrict__ addv, int addStride, int addOff,
    const float* __restrict__ bias, float* __restrict__ out) {
  const int f = threadIdx.x & 15;
  const int d = blockIdx.x * 16 + (threadIdx.x >> 4);
  if (f >= 15) return;
  const int s0 = rowStart[d], s1 = rowStart[d + 1];
  float acc = 0.f;
  int j = s0;
  for (; j + 4 <= s1; j += 4) {
    int2 e0 = eSW[j], e1 = eSW[j + 1], e2 = eSW[j + 2], e3 = eSW[j + 3];
    float v0 = in[(size_t)e0.x * inStride + inOff + f];
    float v1 = in[(size_t)e1.x * inStride + inOff + f];
    float v2 = in[(size_t)e2.x * inStride + inOff + f];
    float v3 = in[(size_t)e3.x * inStride + inOff + f];
    acc = fmaf(__int_as_float(e0.y), v0, acc);
    acc = fmaf(__int_as_float(e1.y), v1, acc);
    acc = fmaf(__int_as_float(e2.y), v2, acc);
    acc = fmaf(__int_as_float(e3.y), v3, acc);
  }
  for (; j < s1; ++j) {
    int2 e = eSW[j];
    acc = fmaf(__int_as_float(e.y), in[(size_t)e.x * inStride + inOff + f], acc);
  }
  float b = bias ? bias[f] : 0.f;
  out[(size_t)d * 15 + f] = addv[(size_t)d * addStride + addOff + f] + acc + b;
}

extern "C" void kernel_launch(void* const* d_in, const int* in_sizes, int n_in,
                              void* d_out, int out_size, void* d_ws, size_t ws_size,
                              hipStream_t stream) {
  const float* x     = (const float*)d_in[0];
  const int*   esrc  = (const int*)d_in[1];
  const int*   edst  = (const int*)d_in[2];
  const float* ew    = (const float*)d_in[3];
  const float* W1    = (const float*)d_in[4];
  const float* b1    = (const float*)d_in[5];
  const float* gamma = (const float*)d_in[6];
  const float* beta  = (const float*)d_in[7];
  const float* mmean = (const float*)d_in[8];
  const float* mvar  = (const float*)d_in[9];
  const float* W2    = (const float*)d_in[10];
  const float* b2    = (const float*)d_in[11];
  const int E = in_sizes[1];
  char* ws = (char*)d_ws;

  // workspace (130.34 MB total, within proven budget)
  unsigned short* xb  = (unsigned short*)(ws);              // 81,920,000  bf16 [20000][2048]
  float*          C0  = (float*)(ws + 81920000);            // 40,960,000  (= Y)
  unsigned short* w1r = (unsigned short*)(ws + 122880000);  //  2,097,152
  int2*           eSW = (int2*)(ws + 124977152);            //  5,120,000
  int*       deg      = (int*)(ws + 130097152);             //     80,128
  int*       rowStart = (int*)(ws + 130177280);             //     80,128
  int*       cursor   = (int*)(ws + 130257408);             //     80,128
  // overlays on xb region (xb dead after k_gemm1)
  unsigned short* Yb3 = (unsigned short*)(ws);              //  5,120,000  bf16
  unsigned short* P   = (unsigned short*)(ws + 5120000);    //  5,120,000  bf16
  unsigned short* Q   = (unsigned short*)(ws + 10240000);   //  5,120,000  bf16
  float*          Hb  = (float*)(ws + 15360000);            // 10,240,000
  float*          Y2  = (float*)(ws + 25600000);            //  4,800,000
  float*          zP  = (float*)(ws + 30400000);            //  1,200,000
  float*          zQ  = (float*)(ws + 31600000);            //  1,200,000
  float*          Y   = C0;
  float*          zout = (float*)d_out;

  // zero accumulators / counters
  hipMemsetAsync(deg, 0, N_NODES * sizeof(int), stream);
  hipMemsetAsync(C0, 0, (size_t)N_NODES * N1 * sizeof(float), stream);

  // CSR by dst (reused by all 6 propagations)
  k_hist<<<(E / 4 + 255) / 256 + 1, 256, 0, stream>>>(edst, deg, E);
  k_scan<<<1, 1024, 0, stream>>>(deg, rowStart, cursor);
  k_scatter<<<(E + 255) / 256, 256, 0, stream>>>(esrc, edst, ew, cursor, eSW, E);

  // GEMM1: Y = x @ [W1_0|W1_1|W1_2|W1_3] (bf16 MFMA, K-split 2, atomic combine)
  k_cvt_x<<<(N_NODES * K_PAD / 8) / 256, 256, 0, stream>>>(x, xb);
  k_cvt_w1<<<128, 256, 0, stream>>>(W1, w1r);
  k_gemm1<<<1280, 256, 0, stream>>>(xb, w1r, C0);
  k_mkYb3<<<(N_NODES * 32) / 256, 256, 0, stream>>>(C0, Yb3);

  // conv1 hops: h = relu(BN(y0 + A(y1 + A(y2 + A*y3)) + b1)); P,Q bf16
  k_prop128c<<<N_NODES / 2, 256, 0, stream>>>(rowStart, eSW, Yb3, Y, N1, 2 * H_DIM,
                                              P, nullptr, b1, gamma, beta, mmean, mvar, 0);
  k_prop128c<<<N_NODES / 2, 256, 0, stream>>>(rowStart, eSW, P, Y, N1, 1 * H_DIM,
                                              Q, nullptr, b1, gamma, beta, mmean, mvar, 0);
  k_prop128c<<<N_NODES / 2, 256, 0, stream>>>(rowStart, eSW, Q, Y, N1, 0,
                                              nullptr, Hb, b1, gamma, beta, mmean, mvar, 1);

  // GEMM2 + conv2 hops: z = u0 + A(u1 + A(u2 + A*u3)) + b2
  k_gemm2<<<N_NODES / 4, 256, 0, stream>>>(Hb, W2, Y2);
  k_prop15<<<N_NODES / 16, 256, 0, stream>>>(rowStart, eSW, Y2, 60, 45, Y2, 60, 30, nullptr, zP);
  k_prop15<<<N_NODES / 16, 256, 0, stream>>>(rowStart, eSW, zP, 15, 0, Y2, 60, 15, nullptr, zQ);
  k_prop15<<<N_NODES / 16, 256, 0, stream>>>(rowStart, eSW, zQ, 15, 0, Y2, 60, 0, b2, zout);
}

// Round 6
// 606.324 us; speedup vs baseline: 1.0611x; 1.0611x over previous
//
#include <hip/hip_runtime.h>
#include <hip/hip_bf16.h>
#include <cstdint>
#include <cstddef>

#define N_NODES 20000
#define F_IN    2000
#define H_DIM   128
#define L_DIM   15
#define K_PAD   2048      // padded K for xb/w1r layouts
#define YS      384       // Y fp32 stride (hops 0..2); hop3 lives in bf16 Yb3
#define BM      128
#define BN      128
#define BK      32
#define I_TILES 157       // ceil(20000/128)

typedef __attribute__((ext_vector_type(4))) float f32x4;
typedef __attribute__((ext_vector_type(8))) short s16x8;
typedef __attribute__((ext_vector_type(8))) unsigned short u16x8;

__device__ __forceinline__ unsigned short f2bf(float f) {
  unsigned int u = __float_as_uint(f);
  u += 0x7fff + ((u >> 16) & 1);   // RNE
  return (unsigned short)(u >> 16);
}

__device__ __forceinline__ unsigned int pkbf(float a, float b) {
  union { __hip_bfloat162 h; unsigned int u; } cv;
  cv.h = __float22bfloat162_rn(make_float2(a, b));
  return cv.u;
}

__device__ __forceinline__ float2 bf2f(unsigned int u) {
  float2 r;
  r.x = __uint_as_float(u << 16);
  r.y = __uint_as_float(u & 0xffff0000u);
  return r;
}

// ---- x (fp32 [20000][2000]) -> bf16 [20000][2048], zero pad cols ----
__global__ __launch_bounds__(256) void k_cvt_x(const float* __restrict__ x,
                                               unsigned short* __restrict__ xb) {
  unsigned int t = blockIdx.x * 256u + threadIdx.x;
  unsigned int row = t >> 8;
  unsigned int colB = (t & 255u) * 8u;
  u16x8 o = {0, 0, 0, 0, 0, 0, 0, 0};
  if (colB < F_IN) {
    const float4 a = *(const float4*)(x + (size_t)row * F_IN + colB);
    const float4 b = *(const float4*)(x + (size_t)row * F_IN + colB + 4);
    o[0] = f2bf(a.x); o[1] = f2bf(a.y); o[2] = f2bf(a.z); o[3] = f2bf(a.w);
    o[4] = f2bf(b.x); o[5] = f2bf(b.y); o[6] = f2bf(b.z); o[7] = f2bf(b.w);
  }
  *(u16x8*)(xb + (size_t)t * 8) = o;
}

// ---- W1 [8000][128] -> bf16 B^T [512][2048] via coalesced read + LDS transpose ----
__global__ __launch_bounds__(256) void k_cvt_w1(const float* __restrict__ W1,
                                                unsigned short* __restrict__ bt) {
  __shared__ unsigned short tile[128 * 67];
  const int hop = blockIdx.x >> 5;
  const int k0  = (blockIdx.x & 31) * 64;
  const int t = threadIdx.x;
#pragma unroll
  for (int it = 0; it < 8; ++it) {
    int f4 = it * 256 + t;
    int r  = f4 >> 5;
    int c4 = f4 & 31;
    int k = k0 + r;
    float4 v = make_float4(0.f, 0.f, 0.f, 0.f);
    if (k < F_IN) v = *(const float4*)(W1 + (size_t)(hop * F_IN + k) * H_DIM + c4 * 4);
    tile[(c4 * 4 + 0) * 67 + r] = f2bf(v.x);
    tile[(c4 * 4 + 1) * 67 + r] = f2bf(v.y);
    tile[(c4 * 4 + 2) * 67 + r] = f2bf(v.z);
    tile[(c4 * 4 + 3) * 67 + r] = f2bf(v.w);
  }
  __syncthreads();
  const int c = t >> 1, kh = (t & 1) * 32;
  unsigned short* dst = bt + (size_t)(hop * 128 + c) * K_PAD + k0 + kh;
  const unsigned short* srcp = tile + c * 67 + kh;
#pragma unroll
  for (int q = 0; q < 4; ++q) {
    u16x8 o;
#pragma unroll
    for (int e = 0; e < 8; ++e) o[e] = srcp[q * 8 + e];
    *(u16x8*)(dst + q * 8) = o;
  }
}

// ---- bf16 MFMA GEMM (R3 structure): j<3 -> fp32 Y[.][384]; j==3 -> bf16 Yb3 ----
// grid = 640 1D; xcd=b&7, i_tile=(b&7)+8*(b>>5), j_tile=(b>>3)&3 -> A-tile L2-shared per XCD
__global__ __launch_bounds__(256) void k_gemm1(const unsigned short* __restrict__ A,
                                               const unsigned short* __restrict__ B,
                                               float* __restrict__ Y,
                                               unsigned short* __restrict__ Yb3) {
  __shared__ unsigned short As[BM * BK];
  __shared__ unsigned short Bs[BN * BK];
  const int b = blockIdx.x;
  const int i_tile = (b & 7) + 8 * (b >> 5);
  const int j_tile = (b >> 3) & 3;
  if (i_tile >= I_TILES) return;
  const int rowA0 = i_tile * BM;
  const int colB0 = j_tile * BN;
  const int tid  = threadIdx.x;
  const int lane = tid & 63;
  const int wave = tid >> 6;
  const int wm = (wave >> 1) * 64;
  const int wn = (wave & 1) * 64;
  const int quad = lane >> 4;
  const int l15  = lane & 15;
  f32x4 acc[4][4] = {};

  for (int kt = 0; kt < K_PAD; kt += BK) {
#pragma unroll
    for (int r = 0; r < 2; ++r) {
      int c = r * 256 + tid;
      int row = c >> 2;
      int kc = (c & 3) * 8;
      const unsigned short* ga = A + (size_t)(rowA0 + row) * K_PAD + kt + kc;
      __builtin_amdgcn_global_load_lds((const __attribute__((address_space(1))) void*)ga,
                                       (__attribute__((address_space(3))) void*)(As + c * 8),
                                       16, 0, 0);
      const unsigned short* gb = B + (size_t)(colB0 + row) * K_PAD + kt + kc;
      __builtin_amdgcn_global_load_lds((const __attribute__((address_space(1))) void*)gb,
                                       (__attribute__((address_space(3))) void*)(Bs + c * 8),
                                       16, 0, 0);
    }
    __syncthreads();
    s16x8 af[4], bfr[4];
#pragma unroll
    for (int i = 0; i < 4; ++i)
      af[i] = *(const s16x8*)(As + (wm + i * 16 + l15) * BK + quad * 8);
#pragma unroll
    for (int j = 0; j < 4; ++j)
      bfr[j] = *(const s16x8*)(Bs + (wn + j * 16 + l15) * BK + quad * 8);
#pragma unroll
    for (int i = 0; i < 4; ++i)
#pragma unroll
      for (int j = 0; j < 4; ++j)
        acc[i][j] = __builtin_amdgcn_mfma_f32_16x16x32_bf16(af[i], bfr[j], acc[i][j], 0, 0, 0);
    __syncthreads();
  }

  // note: i_tile==156 stages A rows >=20000 from past-xb ws bytes (finite bf16);
  // their outputs are discarded by the row guard (D row i depends only on A row i).
#pragma unroll
  for (int i = 0; i < 4; ++i) {
    int row0 = rowA0 + wm + i * 16 + quad * 4;
#pragma unroll
    for (int j = 0; j < 4; ++j) {
      int col16 = wn + j * 16 + l15;          // col within 128-wide tile
#pragma unroll
      for (int r = 0; r < 4; ++r) {
        int row = row0 + r;
        if (row < N_NODES) {
          if (j_tile < 3)
            Y[(size_t)row * YS + colB0 + col16] = acc[i][j][r];
          else
            Yb3[(size_t)row * H_DIM + col16] = f2bf(acc[i][j][r]);
        }
      }
    }
  }
}

// ---- CSR build ----
__global__ __launch_bounds__(256) void k_hist(const int* __restrict__ dst,
                                              int* __restrict__ deg, int E) {
  int i = blockIdx.x * 256 + threadIdx.x;
  int e = i * 4;
  if (e + 4 <= E) {
    int4 d4 = *(const int4*)(dst + e);
    atomicAdd(&deg[d4.x], 1); atomicAdd(&deg[d4.y], 1);
    atomicAdd(&deg[d4.z], 1); atomicAdd(&deg[d4.w], 1);
  } else {
    for (; e < E; ++e) atomicAdd(&deg[dst[e]], 1);
  }
}

__global__ __launch_bounds__(1024) void k_scan(const int* __restrict__ deg,
                                               int* __restrict__ rowStart,
                                               int* __restrict__ cursor) {
  __shared__ int sums[1024];
  const int t = threadIdx.x;
  const int chunk = (N_NODES + 1023) / 1024;
  int lo = t * chunk;
  int hi = lo + chunk; if (hi > N_NODES) hi = N_NODES;
  int s = 0;
  for (int i = lo; i < hi; ++i) s += deg[i];
  sums[t] = s;
  __syncthreads();
  for (int off = 1; off < 1024; off <<= 1) {
    int v = sums[t];
    int u = (t >= off) ? sums[t - off] : 0;
    __syncthreads();
    sums[t] = v + u;
    __syncthreads();
  }
  int run = sums[t] - s;
  for (int i = lo; i < hi; ++i) {
    rowStart[i] = run; cursor[i] = run; run += deg[i];
  }
  if (t == 1023) rowStart[N_NODES] = run;
}

__global__ __launch_bounds__(256) void k_scatter(const int* __restrict__ src,
                                                 const int* __restrict__ dst,
                                                 const float* __restrict__ w,
                                                 int* cursor,
                                                 int2* __restrict__ eSW, int E) {
  int e = blockIdx.x * 256 + threadIdx.x;
  if (e >= E) return;
  int p = atomicAdd(&cursor[dst[e]], 1);
  eSW[p] = make_int2(src[e], __float_as_int(w[e]));
}

// ---- prop128d: 1 wave per dst row; 2 edges per gather instruction ----
// lanes 0-31 handle even-slot edges, 32-63 odd-slot; each lane loads 8 B (4 bf16 feats).
// depth-2 descriptor pipeline: FMA(batch k) overlaps gathers(k+1) and eSW loads(k+2).
__global__ __launch_bounds__(256) void k_prop128d(const int* __restrict__ rowStart,
    const int2* __restrict__ eSW,
    const unsigned short* __restrict__ gsrc,   // bf16 [N_NODES][128]
    const float* __restrict__ addv, int addStride, int addOff,
    unsigned short* __restrict__ outb, float* __restrict__ outf,
    const float* __restrict__ b1, const float* __restrict__ gamma,
    const float* __restrict__ beta, const float* __restrict__ mean,
    const float* __restrict__ var, int doBN) {
  const int lane = threadIdx.x & 63;
  const int wave = threadIdx.x >> 6;
  const int h   = lane >> 5;         // edge-slot parity
  const int sub = lane & 31;         // feature group: f = sub*4 .. sub*4+3
  const int d = blockIdx.x * 4 + wave;
  const int s0 = rowStart[d], s1 = rowStart[d + 1];
  f32x4 acc = {0.f, 0.f, 0.f, 0.f};

  const int nb = (s1 - s0) >> 3;     // batches of 8 edges (4 pairs)
  int j = s0;
  int2 ed0[4], ed1[4];
  uint2 g0[4];
  if (nb > 0) {
#pragma unroll
    for (int i = 0; i < 4; ++i) ed0[i] = eSW[j + 2 * i + h];
#pragma unroll
    for (int i = 0; i < 4; ++i)
      g0[i] = *(const uint2*)(gsrc + (size_t)ed0[i].x * H_DIM + sub * 4);
#pragma unroll
    for (int i = 0; i < 4; ++i)
      ed1[i] = (nb > 1) ? eSW[j + 8 + 2 * i + h] : ed0[i];
  }
  for (int bb = 0; bb < nb; ++bb) {
    uint2 g1[4];
    if (bb + 1 < nb) {
#pragma unroll
      for (int i = 0; i < 4; ++i)
        g1[i] = *(const uint2*)(gsrc + (size_t)ed1[i].x * H_DIM + sub * 4);
    }
    int2 ed2[4];
    if (bb + 2 < nb) {
#pragma unroll
      for (int i = 0; i < 4; ++i) ed2[i] = eSW[j + 16 + 2 * i + h];
    }
#pragma unroll
    for (int i = 0; i < 4; ++i) {
      float w = __int_as_float(ed0[i].y);
      float2 lo = bf2f(g0[i].x), hi = bf2f(g0[i].y);
      acc.x = fmaf(w, lo.x, acc.x); acc.y = fmaf(w, lo.y, acc.y);
      acc.z = fmaf(w, hi.x, acc.z); acc.w = fmaf(w, hi.y, acc.w);
    }
#pragma unroll
    for (int i = 0; i < 4; ++i) { ed0[i] = ed1[i]; g0[i] = g1[i]; }
    if (bb + 2 < nb) {
#pragma unroll
      for (int i = 0; i < 4; ++i) ed1[i] = ed2[i];
    }
    j += 8;
  }
  // tail (< 8 edges), parity-split across halves
  for (int t = s0 + nb * 8 + h; t < s1; t += 2) {
    int2 e = eSW[t];
    uint2 g = *(const uint2*)(gsrc + (size_t)e.x * H_DIM + sub * 4);
    float w = __int_as_float(e.y);
    float2 lo = bf2f(g.x), hi = bf2f(g.y);
    acc.x = fmaf(w, lo.x, acc.x); acc.y = fmaf(w, lo.y, acc.y);
    acc.z = fmaf(w, hi.x, acc.z); acc.w = fmaf(w, hi.y, acc.w);
  }
  // cross-half reduce (h=0 lanes end with full sums for f = sub*4..+3)
  acc.x += __shfl_xor(acc.x, 32);
  acc.y += __shfl_xor(acc.y, 32);
  acc.z += __shfl_xor(acc.z, 32);
  acc.w += __shfl_xor(acc.w, 32);
  if (h) return;
  const int c4 = sub * 4;
  float4 av = *(const float4*)(addv + (size_t)d * addStride + addOff + c4);
  float r0 = av.x + acc.x, r1 = av.y + acc.y;
  float r2 = av.z + acc.z, r3 = av.w + acc.w;
  if (doBN) {
    float4 bb = *(const float4*)(b1 + c4);
    float4 gg = *(const float4*)(gamma + c4);
    float4 be = *(const float4*)(beta + c4);
    float4 mm = *(const float4*)(mean + c4);
    float4 vv = *(const float4*)(var + c4);
    r0 = (r0 + bb.x - mm.x) * rsqrtf(vv.x + 1e-3f) * gg.x + be.x;
    r1 = (r1 + bb.y - mm.y) * rsqrtf(vv.y + 1e-3f) * gg.y + be.y;
    r2 = (r2 + bb.z - mm.z) * rsqrtf(vv.z + 1e-3f) * gg.z + be.z;
    r3 = (r3 + bb.w - mm.w) * rsqrtf(vv.w + 1e-3f) * gg.w + be.w;
    r0 = r0 > 0.f ? r0 : 0.f; r1 = r1 > 0.f ? r1 : 0.f;
    r2 = r2 > 0.f ? r2 : 0.f; r3 = r3 > 0.f ? r3 : 0.f;
    *(float4*)(outf + (size_t)d * H_DIM + c4) = make_float4(r0, r1, r2, r3);
  } else {
    *(uint2*)(outb + (size_t)d * H_DIM + c4) = make_uint2(pkbf(r0, r1), pkbf(r2, r3));
  }
}

// ---- Y2[20000][60] = H @ W2 (4 hop-blocks of [128][15]); fp32 ----
__global__ __launch_bounds__(256) void k_gemm2(const float* __restrict__ Hh,
                                               const float* __restrict__ W2,
                                               float* __restrict__ Y2) {
  __shared__ float w2s[512 * 15];
  for (int i = threadIdx.x; i < 512 * 15; i += 256) w2s[i] = W2[i];
  __syncthreads();
  const int c = threadIdx.x & 63;
  const int d = blockIdx.x * 4 + (threadIdx.x >> 6);
  if (c >= 60 || d >= N_NODES) return;
  const int hop = c / 15, j = c % 15;
  const float4* hr4 = (const float4*)(Hh + (size_t)d * H_DIM);
  float acc = 0.f;
#pragma unroll 8
  for (int k4 = 0; k4 < 32; ++k4) {
    float4 h = hr4[k4];
    const float* wp = w2s + ((hop << 7) + k4 * 4) * 15 + j;
    acc = fmaf(h.x, wp[0],  acc);
    acc = fmaf(h.y, wp[15], acc);
    acc = fmaf(h.z, wp[30], acc);
    acc = fmaf(h.w, wp[45], acc);
  }
  Y2[(size_t)d * 60 + c] = acc;
}

// ---- pull-propagation, 15-wide fp32 ----
__global__ __launch_bounds__(256) void k_prop15(const int* __restrict__ rowStart,
    const int2* __restrict__ eSW,
    const float* __restrict__ in, int inStride, int inOff,
    const float* __restrict__ addv, int addStride, int addOff,
    const float* __restrict__ bias, float* __restrict__ out) {
  const int f = threadIdx.x & 15;
  const int d = blockIdx.x * 16 + (threadIdx.x >> 4);
  if (f >= 15) return;
  const int s0 = rowStart[d], s1 = rowStart[d + 1];
  float acc = 0.f;
  int j = s0;
  for (; j + 4 <= s1; j += 4) {
    int2 e0 = eSW[j], e1 = eSW[j + 1], e2 = eSW[j + 2], e3 = eSW[j + 3];
    float v0 = in[(size_t)e0.x * inStride + inOff + f];
    float v1 = in[(size_t)e1.x * inStride + inOff + f];
    float v2 = in[(size_t)e2.x * inStride + inOff + f];
    float v3 = in[(size_t)e3.x * inStride + inOff + f];
    acc = fmaf(__int_as_float(e0.y), v0, acc);
    acc = fmaf(__int_as_float(e1.y), v1, acc);
    acc = fmaf(__int_as_float(e2.y), v2, acc);
    acc = fmaf(__int_as_float(e3.y), v3, acc);
  }
  for (; j < s1; ++j) {
    int2 e = eSW[j];
    acc = fmaf(__int_as_float(e.y), in[(size_t)e.x * inStride + inOff + f], acc);
  }
  float b = bias ? bias[f] : 0.f;
  out[(size_t)d * 15 + f] = addv[(size_t)d * addStride + addOff + f] + acc + b;
}

extern "C" void kernel_launch(void* const* d_in, const int* in_sizes, int n_in,
                              void* d_out, int out_size, void* d_ws, size_t ws_size,
                              hipStream_t stream) {
  const float* x     = (const float*)d_in[0];
  const int*   esrc  = (const int*)d_in[1];
  const int*   edst  = (const int*)d_in[2];
  const float* ew    = (const float*)d_in[3];
  const float* W1    = (const float*)d_in[4];
  const float* b1    = (const float*)d_in[5];
  const float* gamma = (const float*)d_in[6];
  const float* beta  = (const float*)d_in[7];
  const float* mmean = (const float*)d_in[8];
  const float* mvar  = (const float*)d_in[9];
  const float* W2    = (const float*)d_in[10];
  const float* b2    = (const float*)d_in[11];
  const int E = in_sizes[1];
  char* ws = (char*)d_ws;

  // workspace (125.2 MB total)
  unsigned short* xb  = (unsigned short*)(ws);              // 81,920,000  bf16 [20000][2048]
  float*          Y   = (float*)(ws + 81920000);            // 30,720,000  fp32 [20000][384]
  unsigned short* Yb3 = (unsigned short*)(ws + 112640000);  //  5,120,000  bf16 [20000][128]
  unsigned short* w1r = (unsigned short*)(ws + 117760000);  //  2,097,152
  int2*           eSW = (int2*)(ws + 119857152);            //  5,120,000
  int*       deg      = (int*)(ws + 124977152);             //     80,128
  int*       rowStart = (int*)(ws + 125057280);             //     80,128
  int*       cursor   = (int*)(ws + 125137408);             //     80,128
  // overlays on xb region (xb dead after k_gemm1)
  unsigned short* P   = (unsigned short*)(ws);              //  5,120,000  bf16
  unsigned short* Q   = (unsigned short*)(ws + 5120000);    //  5,120,000  bf16
  float*          Hb  = (float*)(ws + 10240000);            // 10,240,000
  float*          Y2  = (float*)(ws + 20480000);            //  4,800,000
  float*          zP  = (float*)(ws + 25280000);            //  1,200,000
  float*          zQ  = (float*)(ws + 26480000);            //  1,200,000
  float*          zout = (float*)d_out;

  hipMemsetAsync(deg, 0, N_NODES * sizeof(int), stream);

  // CSR by dst (reused by all 6 propagations)
  k_hist<<<(E / 4 + 255) / 256 + 1, 256, 0, stream>>>(edst, deg, E);
  k_scan<<<1, 1024, 0, stream>>>(deg, rowStart, cursor);
  k_scatter<<<(E + 255) / 256, 256, 0, stream>>>(esrc, edst, ew, cursor, eSW, E);

  // GEMM1: [y0|y1|y2] fp32 + y3 bf16, directly from MFMA epilogue
  k_cvt_x<<<(N_NODES * K_PAD / 8) / 256, 256, 0, stream>>>(x, xb);
  k_cvt_w1<<<128, 256, 0, stream>>>(W1, w1r);
  k_gemm1<<<640, 256, 0, stream>>>(xb, w1r, Y, Yb3);

  // conv1 hops: h = relu(BN(y0 + A(y1 + A(y2 + A*y3)) + b1)); P,Q bf16
  k_prop128d<<<N_NODES / 4, 256, 0, stream>>>(rowStart, eSW, Yb3, Y, YS, 256,
                                              P, nullptr, b1, gamma, beta, mmean, mvar, 0);
  k_prop128d<<<N_NODES / 4, 256, 0, stream>>>(rowStart, eSW, P, Y, YS, 128,
                                              Q, nullptr, b1, gamma, beta, mmean, mvar, 0);
  k_prop128d<<<N_NODES / 4, 256, 0, stream>>>(rowStart, eSW, Q, Y, YS, 0,
                                              nullptr, Hb, b1, gamma, beta, mmean, mvar, 1);

  // GEMM2 + conv2 hops: z = u0 + A(u1 + A(u2 + A*u3)) + b2
  k_gemm2<<<N_NODES / 4, 256, 0, stream>>>(Hb, W2, Y2);
  k_prop15<<<N_NODES / 16, 256, 0, stream>>>(rowStart, eSW, Y2, 60, 45, Y2, 60, 30, nullptr, zP);
  k_prop15<<<N_NODES / 16, 256, 0, stream>>>(rowStart, eSW, zP, 15, 0, Y2, 60, 15, nullptr, zQ);
  k_prop15<<<N_NODES / 16, 256, 0, stream>>>(rowStart, eSW, zQ, 15, 0, Y2, 60, 0, b2, zout);
}

// Round 7
// 604.590 us; speedup vs baseline: 1.0641x; 1.0029x over previous
//
#include <hip/hip_runtime.h>
#include <hip/hip_bf16.h>
#include <cstdint>
#include <cstddef>

#define N_NODES 20000
#define F_IN    2000
#define H_DIM   128
#define L_DIM   15
#define K_PAD   2048      // padded K for xb/w1r layouts
#define YS      384       // Y fp32 stride (hops 0..2); hop3 lives in bf16 Yb3
#define BM      128
#define BN      64        // narrower tile: 12KB staged/iter, 1280 blocks
#define BK      32
#define I_TILES 157       // ceil(20000/128)

typedef __attribute__((ext_vector_type(4))) float f32x4;
typedef __attribute__((ext_vector_type(8))) short s16x8;
typedef __attribute__((ext_vector_type(8))) unsigned short u16x8;

__device__ __forceinline__ unsigned short f2bf(float f) {
  unsigned int u = __float_as_uint(f);
  u += 0x7fff + ((u >> 16) & 1);   // RNE
  return (unsigned short)(u >> 16);
}

__device__ __forceinline__ unsigned int pkbf(float a, float b) {
  union { __hip_bfloat162 h; unsigned int u; } cv;
  cv.h = __float22bfloat162_rn(make_float2(a, b));
  return cv.u;
}

__device__ __forceinline__ float2 bf2f(unsigned int u) {
  float2 r;
  r.x = __uint_as_float(u << 16);
  r.y = __uint_as_float(u & 0xffff0000u);
  return r;
}

// ---- x (fp32 [20000][2000]) -> bf16 [20000][2048], zero pad cols ----
__global__ __launch_bounds__(256) void k_cvt_x(const float* __restrict__ x,
                                               unsigned short* __restrict__ xb) {
  unsigned int t = blockIdx.x * 256u + threadIdx.x;
  unsigned int row = t >> 8;
  unsigned int colB = (t & 255u) * 8u;
  u16x8 o = {0, 0, 0, 0, 0, 0, 0, 0};
  if (colB < F_IN) {
    const float4 a = *(const float4*)(x + (size_t)row * F_IN + colB);
    const float4 b = *(const float4*)(x + (size_t)row * F_IN + colB + 4);
    o[0] = f2bf(a.x); o[1] = f2bf(a.y); o[2] = f2bf(a.z); o[3] = f2bf(a.w);
    o[4] = f2bf(b.x); o[5] = f2bf(b.y); o[6] = f2bf(b.z); o[7] = f2bf(b.w);
  }
  *(u16x8*)(xb + (size_t)t * 8) = o;
}

// ---- W1 [8000][128] -> bf16 B^T [512][2048] via coalesced read + LDS transpose ----
__global__ __launch_bounds__(256) void k_cvt_w1(const float* __restrict__ W1,
                                                unsigned short* __restrict__ bt) {
  __shared__ unsigned short tile[128 * 67];
  const int hop = blockIdx.x >> 5;
  const int k0  = (blockIdx.x & 31) * 64;
  const int t = threadIdx.x;
#pragma unroll
  for (int it = 0; it < 8; ++it) {
    int f4 = it * 256 + t;
    int r  = f4 >> 5;
    int c4 = f4 & 31;
    int k = k0 + r;
    float4 v = make_float4(0.f, 0.f, 0.f, 0.f);
    if (k < F_IN) v = *(const float4*)(W1 + (size_t)(hop * F_IN + k) * H_DIM + c4 * 4);
    tile[(c4 * 4 + 0) * 67 + r] = f2bf(v.x);
    tile[(c4 * 4 + 1) * 67 + r] = f2bf(v.y);
    tile[(c4 * 4 + 2) * 67 + r] = f2bf(v.z);
    tile[(c4 * 4 + 3) * 67 + r] = f2bf(v.w);
  }
  __syncthreads();
  const int c = t >> 1, kh = (t & 1) * 32;
  unsigned short* dst = bt + (size_t)(hop * 128 + c) * K_PAD + k0 + kh;
  const unsigned short* srcp = tile + c * 67 + kh;
#pragma unroll
  for (int q = 0; q < 4; ++q) {
    u16x8 o;
#pragma unroll
    for (int e = 0; e < 8; ++e) o[e] = srcp[q * 8 + e];
    *(u16x8*)(dst + q * 8) = o;
  }
}

// ---- bf16 MFMA GEMM, 128x64 tiles: jt<6 -> fp32 Y[.][384]; jt>=6 -> bf16 Yb3 ----
// grid = 1280 1D; xcd=b&7, i_tile=(b&7)+8*(b>>6), j_tile=(b>>3)&7
// All 8 j-blocks of an i_tile share b mod 8 -> same XCD -> A rows L2-shared.
__global__ __launch_bounds__(256) void k_gemm1(const unsigned short* __restrict__ A,
                                               const unsigned short* __restrict__ B,
                                               float* __restrict__ Y,
                                               unsigned short* __restrict__ Yb3) {
  __shared__ unsigned short As[BM * BK];   // 8 KB
  __shared__ unsigned short Bs[BN * BK];   // 4 KB
  const int b = blockIdx.x;
  const int i_tile = (b & 7) + 8 * (b >> 6);
  const int j_tile = (b >> 3) & 7;
  if (i_tile >= I_TILES) return;
  const int rowA0 = i_tile * BM;
  const int colB0 = j_tile * BN;            // 0..448 step 64
  const int tid  = threadIdx.x;
  const int lane = tid & 63;
  const int wave = tid >> 6;
  const int wm = (wave >> 1) * 64;          // 0/64
  const int wn = (wave & 1) * 32;           // 0/32
  const int quad = lane >> 4;
  const int l15  = lane & 15;
  f32x4 acc[4][2] = {};

  for (int kt = 0; kt < K_PAD; kt += BK) {
    // A: 2 instrs/thread (128 rows x 32 k)
#pragma unroll
    for (int r = 0; r < 2; ++r) {
      int c = r * 256 + tid;
      int row = c >> 2;
      int kc = (c & 3) * 8;
      const unsigned short* ga = A + (size_t)(rowA0 + row) * K_PAD + kt + kc;
      __builtin_amdgcn_global_load_lds((const __attribute__((address_space(1))) void*)ga,
                                       (__attribute__((address_space(3))) void*)(As + c * 8),
                                       16, 0, 0);
    }
    // B: 1 instr/thread (64 rows x 32 k)
    {
      int c = tid;
      int row = c >> 2;
      int kc = (c & 3) * 8;
      const unsigned short* gb = B + (size_t)(colB0 + row) * K_PAD + kt + kc;
      __builtin_amdgcn_global_load_lds((const __attribute__((address_space(1))) void*)gb,
                                       (__attribute__((address_space(3))) void*)(Bs + c * 8),
                                       16, 0, 0);
    }
    __syncthreads();
    s16x8 af[4], bfr[2];
#pragma unroll
    for (int i = 0; i < 4; ++i)
      af[i] = *(const s16x8*)(As + (wm + i * 16 + l15) * BK + quad * 8);
#pragma unroll
    for (int j = 0; j < 2; ++j)
      bfr[j] = *(const s16x8*)(Bs + (wn + j * 16 + l15) * BK + quad * 8);
#pragma unroll
    for (int i = 0; i < 4; ++i)
#pragma unroll
      for (int j = 0; j < 2; ++j)
        acc[i][j] = __builtin_amdgcn_mfma_f32_16x16x32_bf16(af[i], bfr[j], acc[i][j], 0, 0, 0);
    __syncthreads();
  }

  // i_tile==156 stages A rows >=20000 from past-xb ws bytes (finite bf16);
  // those outputs are discarded by the row guard.
#pragma unroll
  for (int i = 0; i < 4; ++i) {
    int row0 = rowA0 + wm + i * 16 + quad * 4;
#pragma unroll
    for (int j = 0; j < 2; ++j) {
      int gcol = colB0 + wn + j * 16 + l15;   // 0..511
#pragma unroll
      for (int r = 0; r < 4; ++r) {
        int row = row0 + r;
        if (row < N_NODES) {
          if (j_tile < 6)
            Y[(size_t)row * YS + gcol] = acc[i][j][r];
          else
            Yb3[(size_t)row * H_DIM + (gcol - 384)] = f2bf(acc[i][j][r]);
        }
      }
    }
  }
}

// ---- CSR build ----
__global__ __launch_bounds__(256) void k_hist(const int* __restrict__ dst,
                                              int* __restrict__ deg, int E) {
  int i = blockIdx.x * 256 + threadIdx.x;
  int e = i * 4;
  if (e + 4 <= E) {
    int4 d4 = *(const int4*)(dst + e);
    atomicAdd(&deg[d4.x], 1); atomicAdd(&deg[d4.y], 1);
    atomicAdd(&deg[d4.z], 1); atomicAdd(&deg[d4.w], 1);
  } else {
    for (; e < E; ++e) atomicAdd(&deg[dst[e]], 1);
  }
}

__global__ __launch_bounds__(1024) void k_scan(const int* __restrict__ deg,
                                               int* __restrict__ rowStart,
                                               int* __restrict__ cursor) {
  __shared__ int sums[1024];
  const int t = threadIdx.x;
  const int chunk = (N_NODES + 1023) / 1024;
  int lo = t * chunk;
  int hi = lo + chunk; if (hi > N_NODES) hi = N_NODES;
  int s = 0;
  for (int i = lo; i < hi; ++i) s += deg[i];
  sums[t] = s;
  __syncthreads();
  for (int off = 1; off < 1024; off <<= 1) {
    int v = sums[t];
    int u = (t >= off) ? sums[t - off] : 0;
    __syncthreads();
    sums[t] = v + u;
    __syncthreads();
  }
  int run = sums[t] - s;
  for (int i = lo; i < hi; ++i) {
    rowStart[i] = run; cursor[i] = run; run += deg[i];
  }
  if (t == 1023) rowStart[N_NODES] = run;
}

__global__ __launch_bounds__(256) void k_scatter(const int* __restrict__ src,
                                                 const int* __restrict__ dst,
                                                 const float* __restrict__ w,
                                                 int* cursor,
                                                 int2* __restrict__ eSW, int E) {
  int e = blockIdx.x * 256 + threadIdx.x;
  if (e >= E) return;
  int p = atomicAdd(&cursor[dst[e]], 1);
  eSW[p] = make_int2(src[e], __float_as_int(w[e]));
}

// ---- prop128e: 1 wave per dst row; chunk-16 edges with 8 gathers in flight ----
// lanes 0-31 even-slot edges, 32-63 odd-slot; each lane loads 8 B (4 bf16 feats).
__global__ __launch_bounds__(256) void k_prop128e(const int* __restrict__ rowStart,
    const int2* __restrict__ eSW,
    const unsigned short* __restrict__ gsrc,   // bf16 [N_NODES][128]
    const float* __restrict__ addv, int addStride, int addOff,
    unsigned short* __restrict__ outb, float* __restrict__ outf,
    const float* __restrict__ b1, const float* __restrict__ gamma,
    const float* __restrict__ beta, const float* __restrict__ mean,
    const float* __restrict__ var, int doBN) {
  const int lane = threadIdx.x & 63;
  const int wave = threadIdx.x >> 6;
  const int h   = lane >> 5;         // edge-slot parity
  const int sub = lane & 31;         // feature group: f = sub*4 .. sub*4+3
  const int d = blockIdx.x * 4 + wave;
  const int s0 = rowStart[d], s1 = rowStart[d + 1];
  f32x4 acc = {0.f, 0.f, 0.f, 0.f};

  const int nc = (s1 - s0) >> 4;     // chunks of 16 edges (8 per half-wave)
  int j = s0;
  int2 ed[8];
  if (nc > 0) {
#pragma unroll
    for (int i = 0; i < 8; ++i) ed[i] = eSW[j + 2 * i + h];
  }
  for (int c = 0; c < nc; ++c) {
    uint2 g[8];
#pragma unroll
    for (int i = 0; i < 8; ++i)
      g[i] = *(const uint2*)(gsrc + (size_t)ed[i].x * H_DIM + sub * 4);
    int2 edn[8];
    if (c + 1 < nc) {
#pragma unroll
      for (int i = 0; i < 8; ++i) edn[i] = eSW[j + 16 + 2 * i + h];
    }
#pragma unroll
    for (int i = 0; i < 8; ++i) {
      float w = __int_as_float(ed[i].y);
      float2 lo = bf2f(g[i].x), hi = bf2f(g[i].y);
      acc.x = fmaf(w, lo.x, acc.x); acc.y = fmaf(w, lo.y, acc.y);
      acc.z = fmaf(w, hi.x, acc.z); acc.w = fmaf(w, hi.y, acc.w);
    }
    if (c + 1 < nc) {
#pragma unroll
      for (int i = 0; i < 8; ++i) ed[i] = edn[i];
    }
    j += 16;
  }
  // tail (< 16 edges), parity-split across halves
  for (int t = s0 + nc * 16 + h; t < s1; t += 2) {
    int2 e = eSW[t];
    uint2 g = *(const uint2*)(gsrc + (size_t)e.x * H_DIM + sub * 4);
    float w = __int_as_float(e.y);
    float2 lo = bf2f(g.x), hi = bf2f(g.y);
    acc.x = fmaf(w, lo.x, acc.x); acc.y = fmaf(w, lo.y, acc.y);
    acc.z = fmaf(w, hi.x, acc.z); acc.w = fmaf(w, hi.y, acc.w);
  }
  // cross-half reduce
  acc.x += __shfl_xor(acc.x, 32);
  acc.y += __shfl_xor(acc.y, 32);
  acc.z += __shfl_xor(acc.z, 32);
  acc.w += __shfl_xor(acc.w, 32);
  if (h) return;
  const int c4 = sub * 4;
  float4 av = *(const float4*)(addv + (size_t)d * addStride + addOff + c4);
  float r0 = av.x + acc.x, r1 = av.y + acc.y;
  float r2 = av.z + acc.z, r3 = av.w + acc.w;
  if (doBN) {
    float4 bb = *(const float4*)(b1 + c4);
    float4 gg = *(const float4*)(gamma + c4);
    float4 be = *(const float4*)(beta + c4);
    float4 mm = *(const float4*)(mean + c4);
    float4 vv = *(const float4*)(var + c4);
    r0 = (r0 + bb.x - mm.x) * rsqrtf(vv.x + 1e-3f) * gg.x + be.x;
    r1 = (r1 + bb.y - mm.y) * rsqrtf(vv.y + 1e-3f) * gg.y + be.y;
    r2 = (r2 + bb.z - mm.z) * rsqrtf(vv.z + 1e-3f) * gg.z + be.z;
    r3 = (r3 + bb.w - mm.w) * rsqrtf(vv.w + 1e-3f) * gg.w + be.w;
    r0 = r0 > 0.f ? r0 : 0.f; r1 = r1 > 0.f ? r1 : 0.f;
    r2 = r2 > 0.f ? r2 : 0.f; r3 = r3 > 0.f ? r3 : 0.f;
    *(float4*)(outf + (size_t)d * H_DIM + c4) = make_float4(r0, r1, r2, r3);
  } else {
    *(uint2*)(outb + (size_t)d * H_DIM + c4) = make_uint2(pkbf(r0, r1), pkbf(r2, r3));
  }
}

// ---- Y2[20000][60] = H @ W2 (4 hop-blocks of [128][15]); fp32 ----
__global__ __launch_bounds__(256) void k_gemm2(const float* __restrict__ Hh,
                                               const float* __restrict__ W2,
                                               float* __restrict__ Y2) {
  __shared__ float w2s[512 * 15];
  for (int i = threadIdx.x; i < 512 * 15; i += 256) w2s[i] = W2[i];
  __syncthreads();
  const int c = threadIdx.x & 63;
  const int d = blockIdx.x * 4 + (threadIdx.x >> 6);
  if (c >= 60 || d >= N_NODES) return;
  const int hop = c / 15, j = c % 15;
  const float4* hr4 = (const float4*)(Hh + (size_t)d * H_DIM);
  float acc = 0.f;
#pragma unroll 8
  for (int k4 = 0; k4 < 32; ++k4) {
    float4 h = hr4[k4];
    const float* wp = w2s + ((hop << 7) + k4 * 4) * 15 + j;
    acc = fmaf(h.x, wp[0],  acc);
    acc = fmaf(h.y, wp[15], acc);
    acc = fmaf(h.z, wp[30], acc);
    acc = fmaf(h.w, wp[45], acc);
  }
  Y2[(size_t)d * 60 + c] = acc;
}

// ---- pull-propagation, 15-wide fp32 ----
__global__ __launch_bounds__(256) void k_prop15(const int* __restrict__ rowStart,
    const int2* __restrict__ eSW,
    const float* __restrict__ in, int inStride, int inOff,
    const float* __restrict__ addv, int addStride, int addOff,
    const float* __restrict__ bias, float* __restrict__ out) {
  const int f = threadIdx.x & 15;
  const int d = blockIdx.x * 16 + (threadIdx.x >> 4);
  if (f >= 15) return;
  const int s0 = rowStart[d], s1 = rowStart[d + 1];
  float acc = 0.f;
  int j = s0;
  for (; j + 4 <= s1; j += 4) {
    int2 e0 = eSW[j], e1 = eSW[j + 1], e2 = eSW[j + 2], e3 = eSW[j + 3];
    float v0 = in[(size_t)e0.x * inStride + inOff + f];
    float v1 = in[(size_t)e1.x * inStride + inOff + f];
    float v2 = in[(size_t)e2.x * inStride + inOff + f];
    float v3 = in[(size_t)e3.x * inStride + inOff + f];
    acc = fmaf(__int_as_float(e0.y), v0, acc);
    acc = fmaf(__int_as_float(e1.y), v1, acc);
    acc = fmaf(__int_as_float(e2.y), v2, acc);
    acc = fmaf(__int_as_float(e3.y), v3, acc);
  }
  for (; j < s1; ++j) {
    int2 e = eSW[j];
    acc = fmaf(__int_as_float(e.y), in[(size_t)e.x * inStride + inOff + f], acc);
  }
  float b = bias ? bias[f] : 0.f;
  out[(size_t)d * 15 + f] = addv[(size_t)d * addStride + addOff + f] + acc + b;
}

extern "C" void kernel_launch(void* const* d_in, const int* in_sizes, int n_in,
                              void* d_out, int out_size, void* d_ws, size_t ws_size,
                              hipStream_t stream) {
  const float* x     = (const float*)d_in[0];
  const int*   esrc  = (const int*)d_in[1];
  const int*   edst  = (const int*)d_in[2];
  const float* ew    = (const float*)d_in[3];
  const float* W1    = (const float*)d_in[4];
  const float* b1    = (const float*)d_in[5];
  const float* gamma = (const float*)d_in[6];
  const float* beta  = (const float*)d_in[7];
  const float* mmean = (const float*)d_in[8];
  const float* mvar  = (const float*)d_in[9];
  const float* W2    = (const float*)d_in[10];
  const float* b2    = (const float*)d_in[11];
  const int E = in_sizes[1];
  char* ws = (char*)d_ws;

  // workspace (125.2 MB total)
  unsigned short* xb  = (unsigned short*)(ws);              // 81,920,000  bf16 [20000][2048]
  float*          Y   = (float*)(ws + 81920000);            // 30,720,000  fp32 [20000][384]
  unsigned short* Yb3 = (unsigned short*)(ws + 112640000);  //  5,120,000  bf16 [20000][128]
  unsigned short* w1r = (unsigned short*)(ws + 117760000);  //  2,097,152
  int2*           eSW = (int2*)(ws + 119857152);            //  5,120,000
  int*       deg      = (int*)(ws + 124977152);             //     80,128
  int*       rowStart = (int*)(ws + 125057280);             //     80,128
  int*       cursor   = (int*)(ws + 125137408);             //     80,128
  // overlays on xb region (xb dead after k_gemm1)
  unsigned short* P   = (unsigned short*)(ws);              //  5,120,000  bf16
  unsigned short* Q   = (unsigned short*)(ws + 5120000);    //  5,120,000  bf16
  float*          Hb  = (float*)(ws + 10240000);            // 10,240,000
  float*          Y2  = (float*)(ws + 20480000);            //  4,800,000
  float*          zP  = (float*)(ws + 25280000);            //  1,200,000
  float*          zQ  = (float*)(ws + 26480000);            //  1,200,000
  float*          zout = (float*)d_out;

  hipMemsetAsync(deg, 0, N_NODES * sizeof(int), stream);

  // CSR by dst (reused by all 6 propagations)
  k_hist<<<(E / 4 + 255) / 256 + 1, 256, 0, stream>>>(edst, deg, E);
  k_scan<<<1, 1024, 0, stream>>>(deg, rowStart, cursor);
  k_scatter<<<(E + 255) / 256, 256, 0, stream>>>(esrc, edst, ew, cursor, eSW, E);

  // GEMM1: [y0|y1|y2] fp32 + y3 bf16, directly from MFMA epilogue (128x64 tiles)
  k_cvt_x<<<(N_NODES * K_PAD / 8) / 256, 256, 0, stream>>>(x, xb);
  k_cvt_w1<<<128, 256, 0, stream>>>(W1, w1r);
  k_gemm1<<<1280, 256, 0, stream>>>(xb, w1r, Y, Yb3);

  // conv1 hops: h = relu(BN(y0 + A(y1 + A(y2 + A*y3)) + b1)); P,Q bf16
  k_prop128e<<<N_NODES / 4, 256, 0, stream>>>(rowStart, eSW, Yb3, Y, YS, 256,
                                              P, nullptr, b1, gamma, beta, mmean, mvar, 0);
  k_prop128e<<<N_NODES / 4, 256, 0, stream>>>(rowStart, eSW, P, Y, YS, 128,
                                              Q, nullptr, b1, gamma, beta, mmean, mvar, 0);
  k_prop128e<<<N_NODES / 4, 256, 0, stream>>>(rowStart, eSW, Q, Y, YS, 0,
                                              nullptr, Hb, b1, gamma, beta, mmean, mvar, 1);

  // GEMM2 + conv2 hops: z = u0 + A(u1 + A(u2 + A*u3)) + b2
  k_gemm2<<<N_NODES / 4, 256, 0, stream>>>(Hb, W2, Y2);
  k_prop15<<<N_NODES / 16, 256, 0, stream>>>(rowStart, eSW, Y2, 60, 45, Y2, 60, 30, nullptr, zP);
  k_prop15<<<N_NODES / 16, 256, 0, stream>>>(rowStart, eSW, zP, 15, 0, Y2, 60, 15, nullptr, zQ);
  k_prop15<<<N_NODES / 16, 256, 0, stream>>>(rowStart, eSW, zQ, 15, 0, Y2, 60, 0, b2, zout);
}

// Round 8
// 582.630 us; speedup vs baseline: 1.1042x; 1.0377x over previous
//
#include <hip/hip_runtime.h>
#include <hip/hip_bf16.h>
#include <cstdint>
#include <cstddef>

#define N_NODES 20000
#define F_IN    2000
#define H_DIM   128
#define L_DIM   15
#define K_PAD   2048      // padded K for xb/w1r layouts
#define YS      384       // Y fp32 stride (hops 0..2); hop3 lives in bf16 Yb3
#define BM      128
#define BN      64        // 128x64 tiles: 12KB staged/iter, 1280 blocks
#define BK      32
#define I_TILES 157       // ceil(20000/128)

typedef __attribute__((ext_vector_type(4))) float f32x4;
typedef __attribute__((ext_vector_type(8))) short s16x8;
typedef __attribute__((ext_vector_type(8))) unsigned short u16x8;

__device__ __forceinline__ unsigned short f2bf(float f) {
  unsigned int u = __float_as_uint(f);
  u += 0x7fff + ((u >> 16) & 1);   // RNE
  return (unsigned short)(u >> 16);
}

__device__ __forceinline__ unsigned int pkbf(float a, float b) {
  union { __hip_bfloat162 h; unsigned int u; } cv;
  cv.h = __float22bfloat162_rn(make_float2(a, b));
  return cv.u;
}

__device__ __forceinline__ float2 bf2f(unsigned int u) {
  float2 r;
  r.x = __uint_as_float(u << 16);
  r.y = __uint_as_float(u & 0xffff0000u);
  return r;
}

// ---- x (fp32 [20000][2000]) -> bf16 [20000][2048], zero pad cols ----
__global__ __launch_bounds__(256) void k_cvt_x(const float* __restrict__ x,
                                               unsigned short* __restrict__ xb) {
  unsigned int t = blockIdx.x * 256u + threadIdx.x;
  unsigned int row = t >> 8;
  unsigned int colB = (t & 255u) * 8u;
  u16x8 o = {0, 0, 0, 0, 0, 0, 0, 0};
  if (colB < F_IN) {
    const float4 a = *(const float4*)(x + (size_t)row * F_IN + colB);
    const float4 b = *(const float4*)(x + (size_t)row * F_IN + colB + 4);
    o[0] = f2bf(a.x); o[1] = f2bf(a.y); o[2] = f2bf(a.z); o[3] = f2bf(a.w);
    o[4] = f2bf(b.x); o[5] = f2bf(b.y); o[6] = f2bf(b.z); o[7] = f2bf(b.w);
  }
  *(u16x8*)(xb + (size_t)t * 8) = o;
}

// ---- W1 [8000][128] -> bf16 B^T [512][2048] via coalesced read + LDS transpose ----
__global__ __launch_bounds__(256) void k_cvt_w1(const float* __restrict__ W1,
                                                unsigned short* __restrict__ bt) {
  __shared__ unsigned short tile[128 * 67];
  const int hop = blockIdx.x >> 5;
  const int k0  = (blockIdx.x & 31) * 64;
  const int t = threadIdx.x;
#pragma unroll
  for (int it = 0; it < 8; ++it) {
    int f4 = it * 256 + t;
    int r  = f4 >> 5;
    int c4 = f4 & 31;
    int k = k0 + r;
    float4 v = make_float4(0.f, 0.f, 0.f, 0.f);
    if (k < F_IN) v = *(const float4*)(W1 + (size_t)(hop * F_IN + k) * H_DIM + c4 * 4);
    tile[(c4 * 4 + 0) * 67 + r] = f2bf(v.x);
    tile[(c4 * 4 + 1) * 67 + r] = f2bf(v.y);
    tile[(c4 * 4 + 2) * 67 + r] = f2bf(v.z);
    tile[(c4 * 4 + 3) * 67 + r] = f2bf(v.w);
  }
  __syncthreads();
  const int c = t >> 1, kh = (t & 1) * 32;
  unsigned short* dst = bt + (size_t)(hop * 128 + c) * K_PAD + k0 + kh;
  const unsigned short* srcp = tile + c * 67 + kh;
#pragma unroll
  for (int q = 0; q < 4; ++q) {
    u16x8 o;
#pragma unroll
    for (int e = 0; e < 8; ++e) o[e] = srcp[q * 8 + e];
    *(u16x8*)(dst + q * 8) = o;
  }
}

// ---- bf16 MFMA GEMM, 128x64 tiles: jt<6 -> fp32 Y[.][384]; jt>=6 -> bf16 Yb3 ----
// grid = 1280 1D; xcd=b&7, i_tile=(b&7)+8*(b>>6), j_tile=(b>>3)&7
__global__ __launch_bounds__(256) void k_gemm1(const unsigned short* __restrict__ A,
                                               const unsigned short* __restrict__ B,
                                               float* __restrict__ Y,
                                               unsigned short* __restrict__ Yb3) {
  __shared__ unsigned short As[BM * BK];   // 8 KB
  __shared__ unsigned short Bs[BN * BK];   // 4 KB
  const int b = blockIdx.x;
  const int i_tile = (b & 7) + 8 * (b >> 6);
  const int j_tile = (b >> 3) & 7;
  if (i_tile >= I_TILES) return;
  const int rowA0 = i_tile * BM;
  const int colB0 = j_tile * BN;
  const int tid  = threadIdx.x;
  const int lane = tid & 63;
  const int wave = tid >> 6;
  const int wm = (wave >> 1) * 64;
  const int wn = (wave & 1) * 32;
  const int quad = lane >> 4;
  const int l15  = lane & 15;
  f32x4 acc[4][2] = {};

  for (int kt = 0; kt < K_PAD; kt += BK) {
#pragma unroll
    for (int r = 0; r < 2; ++r) {
      int c = r * 256 + tid;
      int row = c >> 2;
      int kc = (c & 3) * 8;
      const unsigned short* ga = A + (size_t)(rowA0 + row) * K_PAD + kt + kc;
      __builtin_amdgcn_global_load_lds((const __attribute__((address_space(1))) void*)ga,
                                       (__attribute__((address_space(3))) void*)(As + c * 8),
                                       16, 0, 0);
    }
    {
      int c = tid;
      int row = c >> 2;
      int kc = (c & 3) * 8;
      const unsigned short* gb = B + (size_t)(colB0 + row) * K_PAD + kt + kc;
      __builtin_amdgcn_global_load_lds((const __attribute__((address_space(1))) void*)gb,
                                       (__attribute__((address_space(3))) void*)(Bs + c * 8),
                                       16, 0, 0);
    }
    __syncthreads();
    s16x8 af[4], bfr[2];
#pragma unroll
    for (int i = 0; i < 4; ++i)
      af[i] = *(const s16x8*)(As + (wm + i * 16 + l15) * BK + quad * 8);
#pragma unroll
    for (int j = 0; j < 2; ++j)
      bfr[j] = *(const s16x8*)(Bs + (wn + j * 16 + l15) * BK + quad * 8);
#pragma unroll
    for (int i = 0; i < 4; ++i)
#pragma unroll
      for (int j = 0; j < 2; ++j)
        acc[i][j] = __builtin_amdgcn_mfma_f32_16x16x32_bf16(af[i], bfr[j], acc[i][j], 0, 0, 0);
    __syncthreads();
  }

#pragma unroll
  for (int i = 0; i < 4; ++i) {
    int row0 = rowA0 + wm + i * 16 + quad * 4;
#pragma unroll
    for (int j = 0; j < 2; ++j) {
      int gcol = colB0 + wn + j * 16 + l15;
#pragma unroll
      for (int r = 0; r < 4; ++r) {
        int row = row0 + r;
        if (row < N_NODES) {
          if (j_tile < 6)
            Y[(size_t)row * YS + gcol] = acc[i][j][r];
          else
            Yb3[(size_t)row * H_DIM + (gcol - 384)] = f2bf(acc[i][j][r]);
        }
      }
    }
  }
}

// ---- CSR build (padded to multiple of 16 edges per row) ----
__global__ __launch_bounds__(256) void k_hist(const int* __restrict__ dst,
                                              int* __restrict__ deg, int E) {
  int i = blockIdx.x * 256 + threadIdx.x;
  int e = i * 4;
  if (e + 4 <= E) {
    int4 d4 = *(const int4*)(dst + e);
    atomicAdd(&deg[d4.x], 1); atomicAdd(&deg[d4.y], 1);
    atomicAdd(&deg[d4.z], 1); atomicAdd(&deg[d4.w], 1);
  } else {
    for (; e < E; ++e) atomicAdd(&deg[dst[e]], 1);
  }
}

__global__ __launch_bounds__(1024) void k_scan(const int* __restrict__ deg,
                                               int* __restrict__ rowStart,
                                               int* __restrict__ cursor,
                                               int* __restrict__ realEnd) {
  __shared__ int sums[1024];
  const int t = threadIdx.x;
  const int chunk = (N_NODES + 1023) / 1024;
  int lo = t * chunk;
  int hi = lo + chunk; if (hi > N_NODES) hi = N_NODES;
  int s = 0;
  for (int i = lo; i < hi; ++i) s += (deg[i] + 15) & ~15;
  sums[t] = s;
  __syncthreads();
  for (int off = 1; off < 1024; off <<= 1) {
    int v = sums[t];
    int u = (t >= off) ? sums[t - off] : 0;
    __syncthreads();
    sums[t] = v + u;
    __syncthreads();
  }
  int run = sums[t] - s;
  for (int i = lo; i < hi; ++i) {
    rowStart[i] = run; cursor[i] = run; realEnd[i] = run + deg[i];
    run += (deg[i] + 15) & ~15;
  }
  if (t == 1023) rowStart[N_NODES] = run;
}

__global__ __launch_bounds__(256) void k_scatter(const int* __restrict__ src,
                                                 const int* __restrict__ dst,
                                                 const float* __restrict__ w,
                                                 int* cursor,
                                                 int2* __restrict__ eSW, int E) {
  int e = blockIdx.x * 256 + threadIdx.x;
  if (e >= E) return;
  int p = atomicAdd(&cursor[dst[e]], 1);
  eSW[p] = make_int2(src[e], __float_as_int(w[e]));
}

// fill pad slots [realEnd, nextRowStart) with {src=0, w=0}
__global__ __launch_bounds__(256) void k_pad(const int* __restrict__ rowStart,
                                             const int* __restrict__ realEnd,
                                             int2* __restrict__ eSW) {
  int t = blockIdx.x * 256 + threadIdx.x;
  int d = t >> 4, i = t & 15;
  if (d >= N_NODES) return;
  int s = realEnd[d] + i;
  if (s < rowStart[d + 1]) eSW[s] = make_int2(0, 0);
}

// ---- prop128f: 1 wave/row, padded uniform chunks of 16, 4 edges/instruction ----
// lane = eidx*16+s16: eidx picks edge-in-quad, s16 picks 8-feat group (uint4 = 16 B).
// One gather instruction covers 4 full 256 B rows. Reduce via shfl_xor 16,32.
__global__ __launch_bounds__(256) void k_prop128f(const int* __restrict__ rowStart,
    const int2* __restrict__ eSW,
    const unsigned short* __restrict__ gsrc,   // bf16 [N_NODES][128]
    const float* __restrict__ addv, int addStride, int addOff,
    unsigned short* __restrict__ outb, float* __restrict__ outf,
    const float* __restrict__ b1, const float* __restrict__ gamma,
    const float* __restrict__ beta, const float* __restrict__ mean,
    const float* __restrict__ var, int doBN) {
  const int lane = threadIdx.x & 63;
  const int wave = threadIdx.x >> 6;
  const int eidx = lane >> 4;        // 0..3
  const int s16  = lane & 15;        // feats [s16*8, s16*8+8)
  const int d = blockIdx.x * 4 + wave;
  const int s0 = rowStart[d], s1 = rowStart[d + 1];
  f32x4 a0 = {0.f, 0.f, 0.f, 0.f};
  f32x4 a1 = {0.f, 0.f, 0.f, 0.f};

  const int nc = (s1 - s0) >> 4;     // exact: rows padded to multiple of 16
  int j = s0;
  int2 ed0[4], ed1[4];
  if (nc > 0) {
#pragma unroll
    for (int i = 0; i < 4; ++i) ed0[i] = eSW[j + 4 * i + eidx];
  }
  for (int c = 0; c < nc; ++c) {
    uint4 g[4];
#pragma unroll
    for (int i = 0; i < 4; ++i)
      g[i] = *(const uint4*)(gsrc + (size_t)ed0[i].x * H_DIM + s16 * 8);
    if (c + 1 < nc) {
#pragma unroll
      for (int i = 0; i < 4; ++i) ed1[i] = eSW[j + 16 + 4 * i + eidx];
    }
#pragma unroll
    for (int i = 0; i < 4; ++i) {
      float w = __int_as_float(ed0[i].y);
      float2 p0 = bf2f(g[i].x), p1 = bf2f(g[i].y);
      float2 p2 = bf2f(g[i].z), p3 = bf2f(g[i].w);
      a0.x = fmaf(w, p0.x, a0.x); a0.y = fmaf(w, p0.y, a0.y);
      a0.z = fmaf(w, p1.x, a0.z); a0.w = fmaf(w, p1.y, a0.w);
      a1.x = fmaf(w, p2.x, a1.x); a1.y = fmaf(w, p2.y, a1.y);
      a1.z = fmaf(w, p3.x, a1.z); a1.w = fmaf(w, p3.y, a1.w);
    }
#pragma unroll
    for (int i = 0; i < 4; ++i) ed0[i] = ed1[i];
    j += 16;
  }
  // reduce across eidx (4 partials per feature group)
  a0.x += __shfl_xor(a0.x, 16); a0.y += __shfl_xor(a0.y, 16);
  a0.z += __shfl_xor(a0.z, 16); a0.w += __shfl_xor(a0.w, 16);
  a1.x += __shfl_xor(a1.x, 16); a1.y += __shfl_xor(a1.y, 16);
  a1.z += __shfl_xor(a1.z, 16); a1.w += __shfl_xor(a1.w, 16);
  a0.x += __shfl_xor(a0.x, 32); a0.y += __shfl_xor(a0.y, 32);
  a0.z += __shfl_xor(a0.z, 32); a0.w += __shfl_xor(a0.w, 32);
  a1.x += __shfl_xor(a1.x, 32); a1.y += __shfl_xor(a1.y, 32);
  a1.z += __shfl_xor(a1.z, 32); a1.w += __shfl_xor(a1.w, 32);
  if (lane >= 16) return;
  const int c8 = s16 * 8;
  const float* ap = addv + (size_t)d * addStride + addOff + c8;
  float4 av0 = *(const float4*)ap;
  float4 av1 = *(const float4*)(ap + 4);
  float r0 = av0.x + a0.x, r1 = av0.y + a0.y, r2 = av0.z + a0.z, r3 = av0.w + a0.w;
  float r4 = av1.x + a1.x, r5 = av1.y + a1.y, r6 = av1.z + a1.z, r7 = av1.w + a1.w;
  if (doBN) {
    float4 bb0 = *(const float4*)(b1 + c8),    bb1 = *(const float4*)(b1 + c8 + 4);
    float4 gg0 = *(const float4*)(gamma + c8), gg1 = *(const float4*)(gamma + c8 + 4);
    float4 be0 = *(const float4*)(beta + c8),  be1 = *(const float4*)(beta + c8 + 4);
    float4 mm0 = *(const float4*)(mean + c8),  mm1 = *(const float4*)(mean + c8 + 4);
    float4 vv0 = *(const float4*)(var + c8),   vv1 = *(const float4*)(var + c8 + 4);
    r0 = (r0 + bb0.x - mm0.x) * rsqrtf(vv0.x + 1e-3f) * gg0.x + be0.x;
    r1 = (r1 + bb0.y - mm0.y) * rsqrtf(vv0.y + 1e-3f) * gg0.y + be0.y;
    r2 = (r2 + bb0.z - mm0.z) * rsqrtf(vv0.z + 1e-3f) * gg0.z + be0.z;
    r3 = (r3 + bb0.w - mm0.w) * rsqrtf(vv0.w + 1e-3f) * gg0.w + be0.w;
    r4 = (r4 + bb1.x - mm1.x) * rsqrtf(vv1.x + 1e-3f) * gg1.x + be1.x;
    r5 = (r5 + bb1.y - mm1.y) * rsqrtf(vv1.y + 1e-3f) * gg1.y + be1.y;
    r6 = (r6 + bb1.z - mm1.z) * rsqrtf(vv1.z + 1e-3f) * gg1.z + be1.z;
    r7 = (r7 + bb1.w - mm1.w) * rsqrtf(vv1.w + 1e-3f) * gg1.w + be1.w;
    r0 = r0 > 0.f ? r0 : 0.f; r1 = r1 > 0.f ? r1 : 0.f;
    r2 = r2 > 0.f ? r2 : 0.f; r3 = r3 > 0.f ? r3 : 0.f;
    r4 = r4 > 0.f ? r4 : 0.f; r5 = r5 > 0.f ? r5 : 0.f;
    r6 = r6 > 0.f ? r6 : 0.f; r7 = r7 > 0.f ? r7 : 0.f;
    float* op = outf + (size_t)d * H_DIM + c8;
    *(float4*)op = make_float4(r0, r1, r2, r3);
    *(float4*)(op + 4) = make_float4(r4, r5, r6, r7);
  } else {
    *(uint4*)(outb + (size_t)d * H_DIM + c8) =
        make_uint4(pkbf(r0, r1), pkbf(r2, r3), pkbf(r4, r5), pkbf(r6, r7));
  }
}

// ---- Y2[20000][60] = H @ W2 (4 hop-blocks of [128][15]); fp32 ----
__global__ __launch_bounds__(256) void k_gemm2(const float* __restrict__ Hh,
                                               const float* __restrict__ W2,
                                               float* __restrict__ Y2) {
  __shared__ float w2s[512 * 15];
  for (int i = threadIdx.x; i < 512 * 15; i += 256) w2s[i] = W2[i];
  __syncthreads();
  const int c = threadIdx.x & 63;
  const int d = blockIdx.x * 4 + (threadIdx.x >> 6);
  if (c >= 60 || d >= N_NODES) return;
  const int hop = c / 15, j = c % 15;
  const float4* hr4 = (const float4*)(Hh + (size_t)d * H_DIM);
  float acc = 0.f;
#pragma unroll 8
  for (int k4 = 0; k4 < 32; ++k4) {
    float4 h = hr4[k4];
    const float* wp = w2s + ((hop << 7) + k4 * 4) * 15 + j;
    acc = fmaf(h.x, wp[0],  acc);
    acc = fmaf(h.y, wp[15], acc);
    acc = fmaf(h.z, wp[30], acc);
    acc = fmaf(h.w, wp[45], acc);
  }
  Y2[(size_t)d * 60 + c] = acc;
}

// ---- pull-propagation, 15-wide fp32 (padded CSR: tail never runs) ----
__global__ __launch_bounds__(256) void k_prop15(const int* __restrict__ rowStart,
    const int2* __restrict__ eSW,
    const float* __restrict__ in, int inStride, int inOff,
    const float* __restrict__ addv, int addStride, int addOff,
    const float* __restrict__ bias, float* __restrict__ out) {
  const int f = threadIdx.x & 15;
  const int d = blockIdx.x * 16 + (threadIdx.x >> 4);
  if (f >= 15) return;
  const int s0 = rowStart[d], s1 = rowStart[d + 1];
  float acc = 0.f;
  int j = s0;
  for (; j + 4 <= s1; j += 4) {
    int2 e0 = eSW[j], e1 = eSW[j + 1], e2 = eSW[j + 2], e3 = eSW[j + 3];
    float v0 = in[(size_t)e0.x * inStride + inOff + f];
    float v1 = in[(size_t)e1.x * inStride + inOff + f];
    float v2 = in[(size_t)e2.x * inStride + inOff + f];
    float v3 = in[(size_t)e3.x * inStride + inOff + f];
    acc = fmaf(__int_as_float(e0.y), v0, acc);
    acc = fmaf(__int_as_float(e1.y), v1, acc);
    acc = fmaf(__int_as_float(e2.y), v2, acc);
    acc = fmaf(__int_as_float(e3.y), v3, acc);
  }
  for (; j < s1; ++j) {
    int2 e = eSW[j];
    acc = fmaf(__int_as_float(e.y), in[(size_t)e.x * inStride + inOff + f], acc);
  }
  float b = bias ? bias[f] : 0.f;
  out[(size_t)d * 15 + f] = addv[(size_t)d * addStride + addOff + f] + acc + b;
}

extern "C" void kernel_launch(void* const* d_in, const int* in_sizes, int n_in,
                              void* d_out, int out_size, void* d_ws, size_t ws_size,
                              hipStream_t stream) {
  const float* x     = (const float*)d_in[0];
  const int*   esrc  = (const int*)d_in[1];
  const int*   edst  = (const int*)d_in[2];
  const float* ew    = (const float*)d_in[3];
  const float* W1    = (const float*)d_in[4];
  const float* b1    = (const float*)d_in[5];
  const float* gamma = (const float*)d_in[6];
  const float* beta  = (const float*)d_in[7];
  const float* mmean = (const float*)d_in[8];
  const float* mvar  = (const float*)d_in[9];
  const float* W2    = (const float*)d_in[10];
  const float* b2    = (const float*)d_in[11];
  const int E = in_sizes[1];
  char* ws = (char*)d_ws;

  // workspace (127.9 MB total)
  unsigned short* xb  = (unsigned short*)(ws);              // 81,920,000  bf16 [20000][2048]
  float*          Y   = (float*)(ws + 81920000);            // 30,720,000  fp32 [20000][384]
  unsigned short* Yb3 = (unsigned short*)(ws + 112640000);  //  5,120,000  bf16 [20000][128]
  unsigned short* w1r = (unsigned short*)(ws + 117760000);  //  2,097,152
  int2*           eSW = (int2*)(ws + 119857152);            //  7,680,000 (padded: <=940K edges)
  int*       deg      = (int*)(ws + 127537152);             //     80,128
  int*       rowStart = (int*)(ws + 127617280);             //     80,128
  int*       cursor   = (int*)(ws + 127697408);             //     80,128
  int*       realEnd  = (int*)(ws + 127777536);             //     80,128
  // overlays on xb region (xb dead after k_gemm1)
  unsigned short* P   = (unsigned short*)(ws);              //  5,120,000  bf16
  unsigned short* Q   = (unsigned short*)(ws + 5120000);    //  5,120,000  bf16
  float*          Hb  = (float*)(ws + 10240000);            // 10,240,000
  float*          Y2  = (float*)(ws + 20480000);            //  4,800,000
  float*          zP  = (float*)(ws + 25280000);            //  1,200,000
  float*          zQ  = (float*)(ws + 26480000);            //  1,200,000
  float*          zout = (float*)d_out;

  hipMemsetAsync(deg, 0, N_NODES * sizeof(int), stream);

  // padded CSR by dst (reused by all 6 propagations)
  k_hist<<<(E / 4 + 255) / 256 + 1, 256, 0, stream>>>(edst, deg, E);
  k_scan<<<1, 1024, 0, stream>>>(deg, rowStart, cursor, realEnd);
  k_scatter<<<(E + 255) / 256, 256, 0, stream>>>(esrc, edst, ew, cursor, eSW, E);
  k_pad<<<(N_NODES * 16) / 256, 256, 0, stream>>>(rowStart, realEnd, eSW);

  // GEMM1: [y0|y1|y2] fp32 + y3 bf16, directly from MFMA epilogue (128x64 tiles)
  k_cvt_x<<<(N_NODES * K_PAD / 8) / 256, 256, 0, stream>>>(x, xb);
  k_cvt_w1<<<128, 256, 0, stream>>>(W1, w1r);
  k_gemm1<<<1280, 256, 0, stream>>>(xb, w1r, Y, Yb3);

  // conv1 hops: h = relu(BN(y0 + A(y1 + A(y2 + A*y3)) + b1)); P,Q bf16
  k_prop128f<<<N_NODES / 4, 256, 0, stream>>>(rowStart, eSW, Yb3, Y, YS, 256,
                                              P, nullptr, b1, gamma, beta, mmean, mvar, 0);
  k_prop128f<<<N_NODES / 4, 256, 0, stream>>>(rowStart, eSW, P, Y, YS, 128,
                                              Q, nullptr, b1, gamma, beta, mmean, mvar, 0);
  k_prop128f<<<N_NODES / 4, 256, 0, stream>>>(rowStart, eSW, Q, Y, YS, 0,
                                              nullptr, Hb, b1, gamma, beta, mmean, mvar, 1);

  // GEMM2 + conv2 hops: z = u0 + A(u1 + A(u2 + A*u3)) + b2
  k_gemm2<<<N_NODES / 4, 256, 0, stream>>>(Hb, W2, Y2);
  k_prop15<<<N_NODES / 16, 256, 0, stream>>>(rowStart, eSW, Y2, 60, 45, Y2, 60, 30, nullptr, zP);
  k_prop15<<<N_NODES / 16, 256, 0, stream>>>(rowStart, eSW, zP, 15, 0, Y2, 60, 15, nullptr, zQ);
  k_prop15<<<N_NODES / 16, 256, 0, stream>>>(rowStart, eSW, zQ, 15, 0, Y2, 60, 0, b2, zout);
}